// Round 3
// baseline (130.893 us; speedup 1.0000x reference)
//
#include <hip/hip_runtime.h>

// ChamferDistanceMatrixL2: B=32, G=64, N=32, C=3.
// out[b][g1][g2] = mean_n min_m d(n,m) + mean_m min_n d(n,m),
// d(n,m) = s1 + s2 - 2*dot.
//
// v4 = v3 math + v2 occupancy + prefetch:
//   * 4.25 VALU/pair: t = fma(x1,qx,fma(y1,qy,fma(z1,qz,s2))) (3 FMA, s2-seeded),
//     row-min with s1 hoisted (0.5 min3/pair), col-min via min3(colmin,t0+s1a,t1+s1b).
//   * m-split 2-way across lane halves (partner lane^32 handles the other 16 pts
//     of the same g2): register arrays halve -> ~120 VGPR -> 4 waves/SIMD,
//     4096 waves = exactly one residency round. Cross-half: 1 shfl_xor+min per n.
//   * p1 read in 8 chunks of 4 points (3x float4, compile-time offsets),
//     double-buffered: chunk c+1's loads issue before chunk c's compute ->
//     no memory waits inside the distance loops.

__global__ __launch_bounds__(256, 4)
void chamfer_dist_kernel(const float* __restrict__ xyz1,
                         const float* __restrict__ xyz2,
                         float* __restrict__ out) {
    const int b    = blockIdx.x >> 5;                 // 0..31
    const int pair = blockIdx.x & 31;                 // g1 pair index
    const int wave = threadIdx.x >> 6;                // 0..3
    const int lane = threadIdx.x & 63;
    const int g1   = (pair << 1) | (wave >> 1);       // 0..63, wave-uniform
    const int g2   = ((wave & 1) << 5) | (lane & 31); // 0..63
    const int half = lane >> 5;                       // which 16-point m-half

    // ---- register-cache this thread's 16 points of group g2 ----
    const float4* __restrict__ p2v = reinterpret_cast<const float4*>(
        xyz2 + (size_t)(b * 64 + g2) * 96 + half * 48);

    float qx[16], qy[16], qz[16], s2[16], colmin[16];
#pragma unroll
    for (int i = 0; i < 4; ++i) {
        const float4 va = p2v[3 * i + 0];
        const float4 vb = p2v[3 * i + 1];
        const float4 vc = p2v[3 * i + 2];
        const float f[12] = {va.x, va.y, va.z, va.w,
                             vb.x, vb.y, vb.z, vb.w,
                             vc.x, vc.y, vc.z, vc.w};
#pragma unroll
        for (int j = 0; j < 4; ++j) {
            const int m = 4 * i + j;
            const float x = f[3 * j + 0];
            const float y = f[3 * j + 1];
            const float z = f[3 * j + 2];
            s2[m] = fmaf(x, x, fmaf(y, y, z * z));
            qx[m] = -2.0f * x;
            qy[m] = -2.0f * y;
            qz[m] = -2.0f * z;
            colmin[m] = 3.0e38f;
        }
    }

    float sum1 = 0.0f;

    // Process an n-pair: 2 rows x 16 cols of distances.
    auto npair = [&](float xa, float ya, float za,
                     float xb, float yb, float zb) {
        const float s1a = fmaf(xa, xa, fmaf(ya, ya, za * za));
        const float s1b = fmaf(xb, xb, fmaf(yb, yb, zb * zb));
        float ra = 3.0e38f, rb = 3.0e38f;
#pragma unroll
        for (int m = 0; m < 16; m += 2) {
            const float t00 = fmaf(xa, qx[m    ], fmaf(ya, qy[m    ], fmaf(za, qz[m    ], s2[m    ])));
            const float t01 = fmaf(xa, qx[m + 1], fmaf(ya, qy[m + 1], fmaf(za, qz[m + 1], s2[m + 1])));
            const float t10 = fmaf(xb, qx[m    ], fmaf(yb, qy[m    ], fmaf(zb, qz[m    ], s2[m    ])));
            const float t11 = fmaf(xb, qx[m + 1], fmaf(yb, qy[m + 1], fmaf(zb, qz[m + 1], s2[m + 1])));
            ra = fminf(fminf(t00, t01), ra);                                   // v_min3
            rb = fminf(fminf(t10, t11), rb);                                   // v_min3
            colmin[m    ] = fminf(fminf(t00 + s1a, t10 + s1b), colmin[m    ]); // v_min3
            colmin[m + 1] = fminf(fminf(t01 + s1a, t11 + s1b), colmin[m + 1]); // v_min3
        }
        // combine row-mins across the two m-halves (partner lane^32, same g2)
        ra = fminf(ra, __shfl_xor(ra, 32, 64));
        rb = fminf(rb, __shfl_xor(rb, 32, 64));
        sum1 += (s1a + ra) + (s1b + rb);
    };

    // ---- p1: 8 chunks x 4 points (3 float4), double-buffered prefetch ----
    const float4* __restrict__ p1v = reinterpret_cast<const float4*>(
        xyz1 + (size_t)(b * 64 + g1) * 96);

    float4 A0 = p1v[0], A1 = p1v[1], A2 = p1v[2];
#pragma unroll
    for (int c = 0; c < 8; ++c) {
        float4 B0, B1, B2;
        if (c < 7) {                       // compile-time offsets; issues early
            B0 = p1v[3 * c + 3];
            B1 = p1v[3 * c + 4];
            B2 = p1v[3 * c + 5];
        }
        npair(A0.x, A0.y, A0.z, A0.w, A1.x, A1.y);
        npair(A1.z, A1.w, A2.x, A2.y, A2.z, A2.w);
        if (c < 7) { A0 = B0; A1 = B1; A2 = B2; }
    }

    float sum2 = 0.0f;
#pragma unroll
    for (int m = 0; m < 16; ++m) sum2 += colmin[m];
    sum2 += __shfl_xor(sum2, 32, 64);   // combine col-min sums across halves

    if (half == 0)
        out[(size_t)(b * 64 + g1) * 64 + g2] = (sum1 + sum2) * (1.0f / 32.0f);
}

extern "C" void kernel_launch(void* const* d_in, const int* in_sizes, int n_in,
                              void* d_out, int out_size, void* d_ws, size_t ws_size,
                              hipStream_t stream) {
    const float* xyz1 = (const float*)d_in[0];
    const float* xyz2 = (const float*)d_in[1];
    float* out = (float*)d_out;

    dim3 grid(1024);  // 32 b * 32 g1-pairs
    dim3 block(256);  // 4 waves: 2 g1 * 2 g2-half-blocks; lanes = 32 g2 * 2 m-halves
    chamfer_dist_kernel<<<grid, block, 0, stream>>>(xyz1, xyz2, out);
}

// Round 4
// 73.252 us; speedup vs baseline: 1.7869x; 1.7869x over previous
//
#include <hip/hip_runtime.h>
#include <hip/hip_bf16.h>

// ChamferDistanceMatrixL2: B=32, G=64, N=32, C=3.
// out[b][g1][g2] = mean_n min_m d(n,m) + mean_m min_n d(n,m),
// d(n,m) = |xyz1[b,g1,n] - xyz2[b,g2,m]|^2 = s1 + s2 - 2*dot.
//
// One thread per output element. lane = g2, wave = g1 (so p1 loads are
// wave-uniform -> one L1 line request), g2's 32 points register-resident
// as (qx,qy,qz,s2) with q = -2*p2 so each distance is 3 FMA + 1 add + 2 min.
// No LDS, no shuffles, no barriers. ~190 VGPR -> 2 waves/SIMD; grid of
// 2048 waves fills all 1024 SIMDs x2 in a single residency round.
//
// Session history (harness-verified):
//   v1 (this): dur 72.6/73.05 us, kernel ~15 us (below fill in top-5).
//   v2 (m-split, 4 waves/SIMD): 73.49 — occupancy x2 = null -> not latency-bound.
//   v3 (5.0-op/pair math): 77.0 — -16% instrs = null/noise -> kernel is a
//       minor share of dur_us (fill 40us @83% HBM peak + ~17us reset overhead).
//   v4 (lambda+prefetch): 130.9 — VGPR fell to 64, 240 MB/dispatch scratch
//       spill traffic, kernel 73us. REVERTED here.

__global__ __launch_bounds__(256, 2)
void chamfer_dist_kernel(const float* __restrict__ xyz1,
                         const float* __restrict__ xyz2,
                         float* __restrict__ out) {
    const int b    = blockIdx.x >> 4;                               // 0..31
    const int g1   = ((blockIdx.x & 15) << 2) | (threadIdx.x >> 6); // 0..63
    const int g2   = threadIdx.x & 63;                              // 0..63

    // ---- register-cache group g2: q = -2*p2, s2 = |p2|^2 ----
    const float* __restrict__ p2 = xyz2 + (size_t)(b * 64 + g2) * 96;
    float qx[32], qy[32], qz[32], s2[32];
#pragma unroll
    for (int m = 0; m < 32; ++m) {
        const float x = p2[3 * m + 0];
        const float y = p2[3 * m + 1];
        const float z = p2[3 * m + 2];
        s2[m] = fmaf(x, x, fmaf(y, y, z * z));
        qx[m] = -2.0f * x;
        qy[m] = -2.0f * y;
        qz[m] = -2.0f * z;
    }

    float colmin[32];
#pragma unroll
    for (int m = 0; m < 32; ++m) colmin[m] = 3.0e38f;

    const float* __restrict__ p1 = xyz1 + (size_t)(b * 64 + g1) * 96;
    float sum1 = 0.0f;

#pragma unroll 4
    for (int n = 0; n < 32; ++n) {
        const float x1 = p1[3 * n + 0];   // wave-uniform address
        const float y1 = p1[3 * n + 1];
        const float z1 = p1[3 * n + 2];
        const float s1 = fmaf(x1, x1, fmaf(y1, y1, z1 * z1));
        float rmin = 3.0e38f;
#pragma unroll
        for (int m = 0; m < 32; ++m) {
            const float u = s1 + s2[m];
            const float t = fmaf(x1, qx[m], fmaf(y1, qy[m], fmaf(z1, qz[m], u)));
            rmin      = fminf(rmin, t);
            colmin[m] = fminf(colmin[m], t);
        }
        sum1 += rmin;
    }

    float sum2 = 0.0f;
#pragma unroll
    for (int m = 0; m < 32; ++m) sum2 += colmin[m];

    out[(size_t)(b * 64 + g1) * 64 + g2] = (sum1 + sum2) * (1.0f / 32.0f);
}

extern "C" void kernel_launch(void* const* d_in, const int* in_sizes, int n_in,
                              void* d_out, int out_size, void* d_ws, size_t ws_size,
                              hipStream_t stream) {
    const float* xyz1 = (const float*)d_in[0];
    const float* xyz2 = (const float*)d_in[1];
    float* out = (float*)d_out;

    dim3 grid(512);   // 32 b * 16 g1-quads
    dim3 block(256);  // 4 waves (g1) * 64 lanes (g2)
    chamfer_dist_kernel<<<grid, block, 0, stream>>>(xyz1, xyz2, out);
}